// Round 1
// 366.981 us; speedup vs baseline: 1.0802x; 1.0802x over previous
//
#include <hip/hip_runtime.h>
#include <hip/hip_bf16.h>
#include <stdint.h>

// Problem (all fp32 I/O): out[m,o] = sum_k x[m,k] * qw[o,k] + bias[o]
//   qw = ternarize(weight): scale_o = max(max_k |w[o,k]|, 1e-6);
//   t = (w/scale > .5 ? 1 : w/scale < -.5 ? -1 : 0); qw = t*scale.
// Ternary t is exact in bf16; scale stays fp32, applied in the GEMM epilogue.
// M=16384 (B*S), N=2048 (D_out), K=2048 (D_in).
//
// Pass C is the 256x256 8-phase schedule (T1+T2+T3/T4+T5):
//   - 512 thr = 8 waves (2M x 4N), per-wave C tile 128x64 (8x4 MFMA frags)
//   - BK=64, LDS 128 KiB = 2 buf x (A 32K + B 32K), each op split in 2 halves
//   - staging: global_load_lds w=16, LINEAR dest, inverse-swizzled SOURCE
//     (col8 ^= row&7); reads apply the same XOR -> conflict-free ds_read_b128
//   - counted vmcnt(8) at tile boundaries only (one tile = 8 loads/thread in
//     flight); never vmcnt(0) in the main loop
//   - prefetch of tile t+2 into buf(t&1): A halves at P3 (A last read P2),
//     B halves at P4 (B last read P3) -> WAR safe via per-phase end barrier
//   - s_setprio(1) around each 16-MFMA cluster

#define M_DIM 16384
#define N_DIM 2048
#define K_DIM 2048

#define BM 256
#define BN 256
#define BK 64
#define NT (K_DIM / BK)  // 32 K-tiles

typedef __bf16 bf16x8 __attribute__((ext_vector_type(8)));
typedef float f32x4 __attribute__((ext_vector_type(4)));

// ---------------------------------------------------------------------------
// Pass A: x fp32 -> bf16. 8 elements/thread, float4 loads, 16 B store.
// ---------------------------------------------------------------------------
__global__ __launch_bounds__(256) void cvt_x_k(
    const float* __restrict__ x, __hip_bfloat16* __restrict__ xb) {
  const size_t i = ((size_t)blockIdx.x * 256 + threadIdx.x) * 8;
  const float4 a = *(const float4*)(x + i);
  const float4 b = *(const float4*)(x + i + 4);
  bf16x8 o;
  o[0] = (__bf16)a.x; o[1] = (__bf16)a.y; o[2] = (__bf16)a.z; o[3] = (__bf16)a.w;
  o[4] = (__bf16)b.x; o[5] = (__bf16)b.y; o[6] = (__bf16)b.z; o[7] = (__bf16)b.w;
  *(bf16x8*)((__bf16*)xb + i) = o;
}

// ---------------------------------------------------------------------------
// Pass B: per-row ternarize (fp32 in, bf16 ternary out, fp32 scale).
// ---------------------------------------------------------------------------
__global__ __launch_bounds__(256) void ternarize_k(
    const float* __restrict__ w,
    __hip_bfloat16* __restrict__ qw,
    float* __restrict__ scales) {
  const int row = blockIdx.x;
  const float* wr = w + (size_t)row * K_DIM;

  float m = 0.0f;
  for (int k = threadIdx.x; k < K_DIM; k += 256)
    m = fmaxf(m, fabsf(wr[k]));

  for (int off = 32; off > 0; off >>= 1)
    m = fmaxf(m, __shfl_down(m, off, 64));
  __shared__ float wmax[4];
  if ((threadIdx.x & 63) == 0) wmax[threadIdx.x >> 6] = m;
  __syncthreads();
  float scale = fmaxf(fmaxf(wmax[0], wmax[1]), fmaxf(wmax[2], wmax[3]));
  scale = fmaxf(scale, 1e-6f);
  if (threadIdx.x == 0) scales[row] = scale;

  for (int k = threadIdx.x; k < K_DIM; k += 256) {
    const float v = wr[k] / scale;  // identical fp32 op to the reference
    const float t = (v > 0.5f) ? 1.0f : ((v < -0.5f) ? -1.0f : 0.0f);
    qw[(size_t)row * K_DIM + k] = __float2bfloat16(t);
  }
}

// ---------------------------------------------------------------------------
// Pass C: 256x256 8-phase bf16 MFMA GEMM.
// ---------------------------------------------------------------------------
static __device__ __forceinline__ void gload16(const __hip_bfloat16* g,
                                               char* l) {
  // LDS dest is wave-uniform base; HW adds lane*16.
  __builtin_amdgcn_global_load_lds(
      (__attribute__((address_space(1))) void*)const_cast<__hip_bfloat16*>(g),
      (__attribute__((address_space(3))) void*)(l), 16, 0, 0);
}

#define MFMA_(d, a, b) \
  d = __builtin_amdgcn_mfma_f32_16x16x32_bf16(a, b, d, 0, 0, 0)

__global__ __launch_bounds__(512, 2) void gemm_bt_k(
    const __hip_bfloat16* __restrict__ A,   // xb [M,K] bf16
    const __hip_bfloat16* __restrict__ B,   // qw [N,K] bf16 ternary
    const float* __restrict__ scales,       // [N]
    const float* __restrict__ bias,         // [N]
    float* __restrict__ C) {                // [M,N] fp32
  // LDS map (bytes): buf(t&1)*65536 + { A: half*16384 | B: 32768 + half*16384 }
  // Within a half: physical chunk p (16 B) at p*16; p = row*8 + pc; the data
  // stored there is logical column (pc ^ (row&7)) of that row (source-side
  // swizzle), so reads use chunk (lc ^ (row&7)).
  __shared__ __align__(128) char lds[131072];

  const int tid  = threadIdx.x;
  const int wave = tid >> 6;
  const int lane = tid & 63;
  const int quad = lane >> 4;
  const int lrow = lane & 15;
  const int wr = wave >> 2;  // 0..1 (M)
  const int wc = wave & 3;   // 0..3 (N)

  // T1: XCD swizzle. 512 blocks = 8 XCDs x 64; each XCD gets an 8x8 supertile.
  const int orig = blockIdx.x;
  const int wg = (orig & 7) * 64 + (orig >> 3);
  const int bx = wg & 7;   // N blocks (8)
  const int by = wg >> 3;  // M blocks (64)
  const int m0 = by * BM;
  const int n0 = bx * BN;

  // ---- staging addresses (this thread stages rows srow and srow+64) ----
  const int srow  = tid >> 3;                 // 0..63
  const int scol8 = (tid & 7) ^ (srow & 7);   // inverse-swizzled source chunk
  const __hip_bfloat16* Ag = A + (size_t)(m0 + srow) * K_DIM + scol8 * 8;
  const __hip_bfloat16* Bg = B + (size_t)(n0 + srow) * K_DIM + scol8 * 8;
  const int ldsw = wave * 1024;  // wave-uniform chunk base within a half

  // ---- fragment-read addressing (byte offsets inside a half) ----
  // A frag (m,s): row = m*16+lrow, byte = row*128 + ((s*4+quad)^(row&7))*16
  const int axor  = lrow & 7;
  const int aOff0 = lrow * 128 + ((0 + quad) ^ axor) * 16;
  const int aOff1 = lrow * 128 + ((4 + quad) ^ axor) * 16;
  const int bRow  = (wc & 1) * 64 + lrow;     // row within B half
  const int bOff0 = bRow * 128 + ((0 + quad) ^ axor) * 16;
  const int bOff1 = bRow * 128 + ((4 + quad) ^ axor) * 16;
  const int aHalf = wr * 16384;               // wave's A half = wr
  const int bHalf = 32768 + (wc >> 1) * 16384;

#define LDA(buf, m, s) \
  (*(const bf16x8*)(lds + (buf) + aHalf + (m) * 2048 + ((s) ? aOff1 : aOff0)))
#define LDB(buf, n, s) \
  (*(const bf16x8*)(lds + (buf) + bHalf + (n) * 2048 + ((s) ? bOff1 : bOff0)))

  auto STAGE_A = [&](int bufOff, int h, int kk) {
    const __hip_bfloat16* g = Ag + (size_t)h * 128 * K_DIM + kk;
    char* l = lds + bufOff + h * 16384 + ldsw;
    gload16(g, l);
    gload16(g + 64 * K_DIM, l + 8192);
  };
  auto STAGE_B = [&](int bufOff, int h, int kk) {
    const __hip_bfloat16* g = Bg + (size_t)h * 128 * K_DIM + kk;
    char* l = lds + bufOff + 32768 + h * 16384 + ldsw;
    gload16(g, l);
    gload16(g + 64 * K_DIM, l + 8192);
  };

  f32x4 acc[8][4] = {};

  // ---- prologue: stage tiles 0 (buf0) and 1 (buf1); wait tile 0 only ----
  STAGE_A(0, 0, 0);  STAGE_A(0, 1, 0);  STAGE_B(0, 0, 0);  STAGE_B(0, 1, 0);
  STAGE_A(65536, 0, BK); STAGE_A(65536, 1, BK);
  STAGE_B(65536, 0, BK); STAGE_B(65536, 1, BK);
  asm volatile("s_waitcnt vmcnt(8)" ::: "memory");  // tile 0 landed
  __builtin_amdgcn_s_barrier();

  for (int t = 0; t < NT; ++t) {
    const int bufOff = (t & 1) << 16;
    const int kk2 = (t + 2) * BK;
    const bool pf = (t + 2) < NT;

    bf16x8 af0[4][2], af1[4][2], bf0[2][2], bf1[2][2];

    // ---- P1: read af[0-3] + bf[0-1]; MFMA quadrant (m0-3, n0-1) ----
#pragma unroll
    for (int m = 0; m < 4; ++m) {
      af0[m][0] = LDA(bufOff, m, 0);
      af0[m][1] = LDA(bufOff, m, 1);
    }
#pragma unroll
    for (int n = 0; n < 2; ++n) {
      bf0[n][0] = LDB(bufOff, n, 0);
      bf0[n][1] = LDB(bufOff, n, 1);
    }
    __builtin_amdgcn_s_barrier();
    __builtin_amdgcn_s_setprio(1);
#pragma unroll
    for (int m = 0; m < 4; ++m)
#pragma unroll
      for (int n = 0; n < 2; ++n) {
        MFMA_(acc[m][n], af0[m][0], bf0[n][0]);
        MFMA_(acc[m][n], af0[m][1], bf0[n][1]);
      }
    __builtin_amdgcn_s_setprio(0);
    __builtin_amdgcn_s_barrier();

    // ---- P2: read af[4-7]; MFMA quadrant (m4-7, n0-1) ----
#pragma unroll
    for (int m = 0; m < 4; ++m) {
      af1[m][0] = LDA(bufOff, m + 4, 0);
      af1[m][1] = LDA(bufOff, m + 4, 1);
    }
    __builtin_amdgcn_s_barrier();
    __builtin_amdgcn_s_setprio(1);
#pragma unroll
    for (int m = 0; m < 4; ++m)
#pragma unroll
      for (int n = 0; n < 2; ++n) {
        MFMA_(acc[m + 4][n], af1[m][0], bf0[n][0]);
        MFMA_(acc[m + 4][n], af1[m][1], bf0[n][1]);
      }
    __builtin_amdgcn_s_setprio(0);
    __builtin_amdgcn_s_barrier();

    // ---- P3: read bf[2-3]; prefetch A halves of tile t+2 (A freed at P2);
    //          MFMA quadrant (m4-7, n2-3) ----
#pragma unroll
    for (int n = 0; n < 2; ++n) {
      bf1[n][0] = LDB(bufOff, n + 2, 0);
      bf1[n][1] = LDB(bufOff, n + 2, 1);
    }
    if (pf) { STAGE_A(bufOff, 0, kk2); STAGE_A(bufOff, 1, kk2); }
    __builtin_amdgcn_s_barrier();
    __builtin_amdgcn_s_setprio(1);
#pragma unroll
    for (int m = 0; m < 4; ++m)
#pragma unroll
      for (int n = 0; n < 2; ++n) {
        MFMA_(acc[m + 4][n + 2], af1[m][0], bf1[n][0]);
        MFMA_(acc[m + 4][n + 2], af1[m][1], bf1[n][1]);
      }
    __builtin_amdgcn_s_setprio(0);
    __builtin_amdgcn_s_barrier();

    // ---- P4: prefetch B halves of tile t+2 (B freed at P3);
    //          MFMA quadrant (m0-3, n2-3); counted boundary wait ----
    if (pf) { STAGE_B(bufOff, 0, kk2); STAGE_B(bufOff, 1, kk2); }
    __builtin_amdgcn_s_barrier();
    __builtin_amdgcn_s_setprio(1);
#pragma unroll
    for (int m = 0; m < 4; ++m)
#pragma unroll
      for (int n = 0; n < 2; ++n) {
        MFMA_(acc[m][n + 2], af0[m][0], bf1[n][0]);
        MFMA_(acc[m][n + 2], af0[m][1], bf1[n][1]);
      }
    __builtin_amdgcn_s_setprio(0);
    // Tile t+1 must be landed for the next P1. Newer-than-t+1 stages = the 8
    // loads for tile t+2 issued this tile -> vmcnt(8). In the last two tiles
    // nothing newer was issued, so drain.
    if (t < NT - 2)
      asm volatile("s_waitcnt vmcnt(8)" ::: "memory");
    else
      asm volatile("s_waitcnt vmcnt(0)" ::: "memory");
    __builtin_amdgcn_s_barrier();
  }

  // ---- epilogue: C = acc*scale[col] + bias[col] ----
  // C/D layout (16x16x32 bf16): col = lane&15, row = quad*4 + reg.
#pragma unroll
  for (int n = 0; n < 4; ++n) {
    const int col = n0 + wc * 64 + n * 16 + lrow;
    const float s = scales[col];
    const float b = bias[col];
#pragma unroll
    for (int m = 0; m < 8; ++m) {
      const int rbase = m0 + wr * 128 + m * 16 + quad * 4;
#pragma unroll
      for (int r = 0; r < 4; ++r)
        C[(size_t)(rbase + r) * N_DIM + col] = acc[m][n][r] * s + b;
    }
  }
#undef LDA
#undef LDB
}

extern "C" void kernel_launch(void* const* d_in, const int* in_sizes, int n_in,
                              void* d_out, int out_size, void* d_ws, size_t ws_size,
                              hipStream_t stream) {
  const float* x    = (const float*)d_in[0];  // [4,4096,2048] fp32
  const float* w    = (const float*)d_in[1];  // [2048,2048]   fp32
  const float* bias = (const float*)d_in[2];  // [2048]        fp32
  float* out = (float*)d_out;                 // [16384,2048]  fp32

  // ws layout: xb bf16 [M*K] (64 MiB) | qw bf16 [N*K] (8 MiB) | scales fp32 [N]
  __hip_bfloat16* xb = (__hip_bfloat16*)d_ws;
  __hip_bfloat16* qw = (__hip_bfloat16*)((char*)d_ws + (size_t)M_DIM * K_DIM * 2);
  float* scales = (float*)((char*)d_ws + (size_t)M_DIM * K_DIM * 2 + (size_t)N_DIM * K_DIM * 2);

  cvt_x_k<<<dim3((M_DIM * (size_t)K_DIM) / (256 * 8)), dim3(256), 0, stream>>>(x, xb);
  ternarize_k<<<dim3(N_DIM), dim3(256), 0, stream>>>(w, qw, scales);
  gemm_bt_k<<<dim3((M_DIM / BM) * (N_DIM / BN)), dim3(512), 0, stream>>>(xb, qw, scales, bias, out);
}